// Round 7
// baseline (754.971 us; speedup 1.0000x reference)
//
#include <hip/hip_runtime.h>
#include <cstdint>
#include <cstddef>

typedef _Float16 h8 __attribute__((ext_vector_type(8)));
typedef float f4 __attribute__((ext_vector_type(4)));
typedef float f16f __attribute__((ext_vector_type(16)));

#define DEV static __device__ __forceinline__

DEV void gld16(const void* g, void* l) {
  __builtin_amdgcn_global_load_lds(
      (const __attribute__((address_space(1))) void*)g,
      (__attribute__((address_space(3))) void*)l, 16, 0, 0);
}

// ---------- FastKAN prep: LayerNorm + RBF basis + SiLU -> Acat [M][6912] fp16
__global__ __launch_bounds__(256)
void kan_prep(const float* __restrict__ X, const float* __restrict__ lnw,
              const float* __restrict__ lnb, _Float16* __restrict__ Acat) {
  const int row = blockIdx.x;
  const int tid = threadIdx.x;
  const float* xr = X + (size_t)row * 768;
  float xv[3];
  xv[0] = xr[tid]; xv[1] = xr[tid + 256]; xv[2] = xr[tid + 512];
  float s = xv[0] + xv[1] + xv[2];
  float q = xv[0] * xv[0] + xv[1] * xv[1] + xv[2] * xv[2];
#pragma unroll
  for (int off = 32; off; off >>= 1) {
    s += __shfl_xor(s, off);
    q += __shfl_xor(q, off);
  }
  __shared__ float rs_[4], rq_[4];
  const int wave = tid >> 6;
  if ((tid & 63) == 0) { rs_[wave] = s; rq_[wave] = q; }
  __syncthreads();
  s = rs_[0] + rs_[1] + rs_[2] + rs_[3];
  q = rq_[0] + rq_[1] + rq_[2] + rq_[3];
  const float mu = s * (1.0f / 768.0f);
  const float var = q * (1.0f / 768.0f) - mu * mu;
  const float rsig = rsqrtf(var + 1e-5f);
  _Float16* out = Acat + (size_t)row * 6912;
#pragma unroll
  for (int i = 0; i < 3; ++i) {
    const int c = tid + i * 256;
    const float x = xv[i];
    const float h = (x - mu) * rsig * lnw[c] + lnb[c];
    union { h8 v; _Float16 u[8]; } bs;
#pragma unroll
    for (int g = 0; g < 8; ++g) {
      const float gv = -2.0f + (4.0f / 7.0f) * (float)g;
      const float t = (h - gv) * 1.75f;  // 1/DENOM = 7/4
      bs.u[g] = (_Float16)__expf(-t * t);
    }
    *(h8*)(out + c * 8) = bs.v;
    out[6144 + c] = (_Float16)(x / (1.0f + __expf(-x)));  // silu
  }
}

// ---------- weight cast + FRAGMENT-SWIZZLE: W fp32 [K][N] -> Bp fp16 in exact
// MFMA B-fragment order: 16B frag (n, k..k+7) at elem addr
//   ((n>>5)*nkt + (k>>6))*2048 + (((k>>4)&3)*64 + (n&31) + 32*((k>>3)&1))*8
__global__ __launch_bounds__(256)
void wt_cast(const float* __restrict__ W, _Float16* __restrict__ Bp,
             int N, int koff, int nkt) {
  __shared__ float t[32][33];
  const int k0 = blockIdx.x * 32, n0 = blockIdx.y * 32;
  const int tx = threadIdx.x & 31, ty = threadIdx.x >> 5;
#pragma unroll
  for (int i = 0; i < 4; ++i)
    t[ty + i * 8][tx] = W[(size_t)(k0 + ty + i * 8) * N + n0 + tx];
  __syncthreads();
  const int f = threadIdx.x;
  if (f < 128) {
    const int nn = f & 31, cc = f >> 5;          // cc: which 8-elem k-chunk
    union { h8 v; _Float16 u[8]; } bs;
#pragma unroll
    for (int j = 0; j < 8; ++j) bs.u[j] = (_Float16)t[cc * 8 + j][nn];
    const int kg = koff + k0 + cc * 8;           // global k of chunk start
    const int nt = (n0 + nn) >> 5;
    const size_t addr = ((size_t)nt * nkt + (kg >> 6)) * 2048 +
                        (size_t)((((kg >> 4) & 3) * 64 + nn + 32 * ((kg >> 3) & 1))) * 8;
    *(h8*)(Bp + addr) = bs.v;
  }
}

// ---------- V transpose: qkv fp16 [8192][2304] -> Vt [96*64][1024]
__global__ __launch_bounds__(256)
void v_transpose(const _Float16* __restrict__ qkv, _Float16* __restrict__ Vt) {
  const int bh = blockIdx.z, hh = bh % 12, b = bh / 12;
  const int kvb = blockIdx.x * 32, db = blockIdx.y * 32;
  __shared__ _Float16 t[32][33];
  const int tx = threadIdx.x & 31, ty = threadIdx.x >> 5;
#pragma unroll
  for (int i = 0; i < 4; ++i) {
    const int kv = kvb + ty + i * 8;
    t[ty + i * 8][tx] = qkv[(size_t)(b * 1024 + kv) * 2304 + 1536 + hh * 64 + db + tx];
  }
  __syncthreads();
#pragma unroll
  for (int i = 0; i < 4; ++i) {
    const int d = db + ty + i * 8;
    Vt[(size_t)(bh * 64 + d) * 1024 + kvb + tx] = t[tx][ty + i * 8];
  }
}

// ---------- shared GEMM building blocks (r7 geometry, r13 barrier)
#define LOAD_B(dst)                                       \
  {                                                       \
    _Pragma("unroll") for (int ni = 0; ni < 2; ++ni) {    \
      _Pragma("unroll") for (int ks = 0; ks < 4; ++ks)    \
        dst[ni][ks] = *(const h8*)(bpp[ni] + ks * 512);   \
      bpp[ni] += 2048;                                    \
    }                                                     \
  }
#define LOAD_A(buf)                                       \
  {                                                       \
    _Pragma("unroll") for (int i = 0; i < 4; ++i) {       \
      gld16(ap[i], (buf) + alOff[i]);                     \
      ap[i] += 64;                                        \
    }                                                     \
  }
#define MFMA_STEP(buf, br)                                \
  {                                                       \
    const h8* A8 = (const h8*)(buf);                      \
    _Pragma("unroll") for (int ks = 0; ks < 4; ++ks) {    \
      const int o = (ks * 2 + half) ^ swz;                \
      h8 af0 = A8[(wm + l31) * 8 + o];                    \
      h8 af1 = A8[(wm + 32 + l31) * 8 + o];               \
      acc[0][0] = __builtin_amdgcn_mfma_f32_32x32x16_f16(af0, br[0][ks], acc[0][0], 0, 0, 0); \
      acc[0][1] = __builtin_amdgcn_mfma_f32_32x32x16_f16(af0, br[1][ks], acc[0][1], 0, 0, 0); \
      acc[1][0] = __builtin_amdgcn_mfma_f32_32x32x16_f16(af1, br[0][ks], acc[1][0], 0, 0, 0); \
      acc[1][1] = __builtin_amdgcn_mfma_f32_32x32x16_f16(af1, br[1][ks], acc[1][1], 0, 0, 0); \
    }                                                     \
  }
// r13 counted barrier. Issue order per half-body: A-DMA(next) FIRST, then
// B reg-loads(next). At the barrier the 4 A-DMAs are the OLDEST outstanding
// vm-ops (ledger: outstanding = A(next)x4 + B(next)x8 = 12 at every barrier),
// so vmcnt(8) retires exactly them; the B-loads ride through and get waited
// by the compiler's own vmcnt before their MFMA use — a per-wave wait that
// the partner block's waves can cover (m114), unlike the all-wave barrier
// drain of __syncthreads. lgkmcnt(0): ds_reads of the buffer about to be
// overwritten retired before any wave passes.
#define WB8()                                                          \
  {                                                                    \
    asm volatile("s_waitcnt vmcnt(8) lgkmcnt(0)" ::: "memory");        \
    __builtin_amdgcn_s_barrier();                                      \
  }

// ---------- fp16 GEMM r13: r7 geometry EXACTLY (BM=BN=128, 256 thr, 2x16KB
// A dbuf, 2 blocks/CU) — single change vs r7: A-first issue + WB8 barrier.
template <bool F16OUT>
__global__ __launch_bounds__(256, 2)
void gemm_bt(const _Float16* __restrict__ A, const _Float16* __restrict__ Bp,
             const float* __restrict__ bias, void* __restrict__ Cout,
             int N, int ldK, int kLen, size_t sliceStride) {
  __shared__ __align__(16) _Float16 As[2 * 128 * 64];
  _Float16* As0 = As;
  _Float16* As1 = As + 128 * 64;
  const int tid = threadIdx.x;
  const int lane = tid & 63, wave = tid >> 6;
  const int gx = gridDim.x;
  const int lin = blockIdx.y * gx + blockIdx.x;
  const int xcd = lin & 7, pos = lin >> 3;
  const int bandH = gridDim.y >> 3;
  const int bm = (xcd * bandH + pos / gx) * 128;
  const int bn = (pos % gx) * 128;
  const int slice = blockIdx.z;
  const int kOff = slice * kLen;
  const int rsub = lane >> 3;
  const int l7 = lane & 7;
  const int l31 = lane & 31, half = lane >> 5;
  const int wm = (wave >> 1) * 64, wn = (wave & 1) * 64;
  const _Float16* ap[4];
  int alOff[4];
#pragma unroll
  for (int i = 0; i < 4; ++i) {
    const int ch = wave * 4 + i;
    const int ksw = (l7 ^ rsub ^ ((ch & 3) << 1)) * 8;
    ap[i] = A + (size_t)(bm + ch * 8 + rsub) * ldK + kOff + ksw;
    alOff[i] = ch * 512;
  }
  const size_t nktTot = (size_t)(ldK >> 6);
  const int kt0 = kOff >> 6;
  const _Float16* bpp[2];
#pragma unroll
  for (int ni = 0; ni < 2; ++ni)
    bpp[ni] = Bp + ((size_t)((bn >> 5) + (wn >> 5) + ni) * nktTot + kt0) * 2048 + lane * 8;

  f16f acc[2][2] = {};
  const int swz = l7 ^ ((rsub & 3) << 1);
  const int nkt = kLen >> 6;                  // even (108)
  h8 bregA[2][4], bregB[2][4];
  LOAD_A(As0);                                // A first: oldest vm-ops
  LOAD_B(bregA);
  for (int kt = 0; kt < nkt; kt += 2) {
    WB8();                                    // waits A(kt) only; B rides
    if (kt + 1 < nkt) { LOAD_A(As1); LOAD_B(bregB); }
    MFMA_STEP(As0, bregA);                    // compiler waits B(kt) here
    WB8();                                    // waits A(kt+1) only
    if (kt + 2 < nkt) { LOAD_A(As0); LOAD_B(bregA); }
    MFMA_STEP(As1, bregB);
  }
  // epilogue: 32x32 C/D layout col=lane&31, row=(reg&3)+8*(reg>>2)+4*(lane>>5)
#pragma unroll
  for (int ni = 0; ni < 2; ++ni) {
    const int col = bn + wn + ni * 32 + l31;
    const float bv = bias ? bias[col] : 0.0f;
#pragma unroll
    for (int mi = 0; mi < 2; ++mi) {
      const int rb = bm + wm + mi * 32 + 4 * half;
#pragma unroll
      for (int reg = 0; reg < 16; ++reg) {
        const int r = rb + (reg & 3) + 8 * (reg >> 2);
        const float v = acc[mi][ni][reg] + bv;
        if (F16OUT)
          ((_Float16*)Cout)[(size_t)r * N + col] = (_Float16)v;
        else
          ((float*)Cout + slice * sliceStride)[(size_t)r * N + col] = v;
      }
    }
  }
}

// ---------- flash attention (r7 structure + T5 setprio on MFMA clusters)
__global__ __launch_bounds__(256)
void attn(const _Float16* __restrict__ qkv, const _Float16* __restrict__ Vt,
          float* __restrict__ ctx) {
  __shared__ __align__(16) _Float16 Qs[128 * 64];
  __shared__ __align__(16) _Float16 Ks[64 * 64];
  __shared__ __align__(16) _Float16 Vs[64 * 64];
  __shared__ __align__(16) _Float16 Ps[4 * 32 * 72];
  const int tid = threadIdx.x;
  const int lane = tid & 63, wave = tid >> 6;
  const int bh = blockIdx.y, hh = bh % 12, b = bh / 12;
  const int qt = blockIdx.x;
  const int rsub = lane >> 3;
  const int ksw = ((lane & 7) ^ rsub) * 8;
#pragma unroll
  for (int i = 0; i < 4; ++i) {
    const int ch = wave * 4 + i;
    const int row = ch * 8 + rsub;
    gld16(qkv + (size_t)(b * 1024 + qt * 128 + row) * 2304 + hh * 64 + ksw, Qs + ch * 512);
  }
  const int l16 = lane & 15, quad = lane >> 4, r7 = l16 & 7;
  f4 acc_o[2][4] = {};
  float m_old[2][4], l_sum[2][4];
#pragma unroll
  for (int mi = 0; mi < 2; ++mi)
#pragma unroll
    for (int j = 0; j < 4; ++j) { m_old[mi][j] = -1e30f; l_sum[mi][j] = 0.0f; }

  _Float16* Pw = Ps + wave * (32 * 72);

  for (int kv0 = 0; kv0 < 1024; kv0 += 64) {
#pragma unroll
    for (int i = 0; i < 2; ++i) {
      const int ch = wave * 2 + i;
      const int row = ch * 8 + rsub;
      gld16(qkv + (size_t)(b * 1024 + kv0 + row) * 2304 + 768 + hh * 64 + ksw, Ks + ch * 512);
      gld16(Vt + (size_t)(bh * 64 + row) * 1024 + kv0 + ksw, Vs + ch * 512);
    }
    __syncthreads();
    const h8* Q8 = (const h8*)Qs;
    const h8* K8 = (const h8*)Ks;
    const h8* V8 = (const h8*)Vs;
    f4 s[2][4] = {};
    __builtin_amdgcn_s_setprio(1);
#pragma unroll
    for (int ks = 0; ks < 2; ++ks) {
      const int kq = (ks * 4 + quad) ^ r7;
      h8 qf[2], kf[4];
#pragma unroll
      for (int mi = 0; mi < 2; ++mi) qf[mi] = Q8[(wave * 32 + mi * 16 + l16) * 8 + kq];
#pragma unroll
      for (int ni = 0; ni < 4; ++ni) kf[ni] = K8[(ni * 16 + l16) * 8 + kq];
#pragma unroll
      for (int mi = 0; mi < 2; ++mi)
#pragma unroll
        for (int ni = 0; ni < 4; ++ni)
          s[mi][ni] = __builtin_amdgcn_mfma_f32_16x16x32_f16(qf[mi], kf[ni], s[mi][ni], 0, 0, 0);
    }
    __builtin_amdgcn_s_setprio(0);
#pragma unroll
    for (int mi = 0; mi < 2; ++mi)
#pragma unroll
      for (int ni = 0; ni < 4; ++ni) s[mi][ni] *= 0.125f;  // d^-0.5, d=64
#pragma unroll
    for (int mi = 0; mi < 2; ++mi) {
#pragma unroll
      for (int j = 0; j < 4; ++j) {
        float vm = fmaxf(fmaxf(s[mi][0][j], s[mi][1][j]), fmaxf(s[mi][2][j], s[mi][3][j]));
#pragma unroll
        for (int off = 1; off < 16; off <<= 1) vm = fmaxf(vm, __shfl_xor(vm, off));
        const float mn = fmaxf(m_old[mi][j], vm);
        const float alpha = __expf(m_old[mi][j] - mn);
        float rs = 0.0f;
#pragma unroll
        for (int ni = 0; ni < 4; ++ni) {
          const float p = __expf(s[mi][ni][j] - mn);
          s[mi][ni][j] = p;
          rs += p;
        }
#pragma unroll
        for (int off = 1; off < 16; off <<= 1) rs += __shfl_xor(rs, off);
        l_sum[mi][j] = l_sum[mi][j] * alpha + rs;
        m_old[mi][j] = mn;
#pragma unroll
        for (int ni = 0; ni < 4; ++ni) acc_o[mi][ni][j] *= alpha;
      }
    }
#pragma unroll
    for (int mi = 0; mi < 2; ++mi)
#pragma unroll
      for (int ni = 0; ni < 4; ++ni)
#pragma unroll
        for (int j = 0; j < 4; ++j)
          Pw[(mi * 16 + quad * 4 + j) * 72 + ni * 16 + l16] = (_Float16)s[mi][ni][j];
    __builtin_amdgcn_s_setprio(1);
#pragma unroll
    for (int ks = 0; ks < 2; ++ks) {
      const int kq = ks * 4 + quad;
      h8 pf[2], vf[4];
#pragma unroll
      for (int mi = 0; mi < 2; ++mi) pf[mi] = *(const h8*)(Pw + (mi * 16 + l16) * 72 + kq * 8);
#pragma unroll
      for (int ni = 0; ni < 4; ++ni) vf[ni] = V8[(ni * 16 + l16) * 8 + (kq ^ r7)];
#pragma unroll
      for (int mi = 0; mi < 2; ++mi)
#pragma unroll
        for (int ni = 0; ni < 4; ++ni)
          acc_o[mi][ni] = __builtin_amdgcn_mfma_f32_16x16x32_f16(pf[mi], vf[ni], acc_o[mi][ni], 0, 0, 0);
    }
    __builtin_amdgcn_s_setprio(0);
    __syncthreads();
  }
#pragma unroll
  for (int mi = 0; mi < 2; ++mi) {
#pragma unroll
    for (int j = 0; j < 4; ++j) {
      const float inv = 1.0f / l_sum[mi][j];
      const int tok = b * 1024 + qt * 128 + wave * 32 + mi * 16 + quad * 4 + j;
      float* cr = ctx + (size_t)tok * 768 + hh * 64;
#pragma unroll
      for (int ni = 0; ni < 4; ++ni) cr[ni * 16 + l16] = acc_o[mi][ni][j] * inv;
    }
  }
}

extern "C" void kernel_launch(void* const* d_in, const int* in_sizes, int n_in,
                              void* d_out, int out_size, void* d_ws, size_t ws_size,
                              hipStream_t stream) {
  (void)in_sizes; (void)n_in; (void)out_size; (void)ws_size;
  const float* x    = (const float*)d_in[0];
  const float* qlnw = (const float*)d_in[1];
  const float* qlnb = (const float*)d_in[2];
  const float* qsw  = (const float*)d_in[3];
  const float* qbw  = (const float*)d_in[4];
  const float* qbb  = (const float*)d_in[5];
  const float* plnw = (const float*)d_in[6];
  const float* plnb = (const float*)d_in[7];
  const float* psw  = (const float*)d_in[8];
  const float* pbw  = (const float*)d_in[9];
  const float* pbb  = (const float*)d_in[10];
  float* out = (float*)d_out;

  // workspace layout (fp16 unless noted), ~231 MB total
  _Float16* WtQ  = (_Float16*)d_ws;                  // [2304][6912] fragment-order
  _Float16* WtP  = WtQ + (size_t)2304 * 6912;        // [768][6912] fragment-order
  _Float16* Acat = WtP + (size_t)768 * 6912;         // [8192][6912] (reused)
  _Float16* QKV  = Acat + (size_t)8192 * 6912;       // [8192][2304]
  _Float16* Vt   = QKV + (size_t)8192 * 2304;        // [96*64][1024]
  float* CTX = (float*)(Vt + (size_t)96 * 64 * 1024);  // [8192][768] fp32

  dim3 blk(256);
  // weights -> fp16, fragment-swizzled (K total 6912 -> nkt=108)
  wt_cast<<<dim3(192, 72), blk, 0, stream>>>(qsw, WtQ, 2304, 0, 108);
  wt_cast<<<dim3(24, 72),  blk, 0, stream>>>(qbw, WtQ, 2304, 6144, 108);
  wt_cast<<<dim3(192, 24), blk, 0, stream>>>(psw, WtP, 768, 0, 108);
  wt_cast<<<dim3(24, 24),  blk, 0, stream>>>(pbw, WtP, 768, 6144, 108);
  // FastKAN 1 -> qkv
  kan_prep<<<8192, blk, 0, stream>>>(x, qlnw, qlnb, Acat);
  gemm_bt<true><<<dim3(2304 / 128, 8192 / 128, 1), blk, 0, stream>>>(
      Acat, WtQ, qbb, QKV, 2304, 6912, 6912, 0);
  // attention
  v_transpose<<<dim3(32, 2, 96), blk, 0, stream>>>(QKV, Vt);
  attn<<<dim3(8, 96), blk, 0, stream>>>(QKV, Vt, CTX);
  // FastKAN 2 -> out (single slice K=6912, bias in epilogue)
  kan_prep<<<8192, blk, 0, stream>>>(CTX, plnw, plnb, Acat);
  gemm_bt<false><<<dim3(768 / 128, 8192 / 128, 1), blk, 0, stream>>>(
      Acat, WtP, pbb, out, 768, 6912, 6912, 0);
}

// Round 8
// 733.397 us; speedup vs baseline: 1.0294x; 1.0294x over previous
//
#include <hip/hip_runtime.h>
#include <cstdint>
#include <cstddef>

typedef _Float16 h8 __attribute__((ext_vector_type(8)));
typedef float f4 __attribute__((ext_vector_type(4)));
typedef float f16f __attribute__((ext_vector_type(16)));

#define DEV static __device__ __forceinline__

DEV void gld16(const void* g, void* l) {
  __builtin_amdgcn_global_load_lds(
      (const __attribute__((address_space(1))) void*)g,
      (__attribute__((address_space(3))) void*)l, 16, 0, 0);
}

// ---------- FastKAN prep: LayerNorm + RBF basis + SiLU -> Acat [M][6912] fp16
__global__ __launch_bounds__(256)
void kan_prep(const float* __restrict__ X, const float* __restrict__ lnw,
              const float* __restrict__ lnb, _Float16* __restrict__ Acat) {
  const int row = blockIdx.x;
  const int tid = threadIdx.x;
  const float* xr = X + (size_t)row * 768;
  float xv[3];
  xv[0] = xr[tid]; xv[1] = xr[tid + 256]; xv[2] = xr[tid + 512];
  float s = xv[0] + xv[1] + xv[2];
  float q = xv[0] * xv[0] + xv[1] * xv[1] + xv[2] * xv[2];
#pragma unroll
  for (int off = 32; off; off >>= 1) {
    s += __shfl_xor(s, off);
    q += __shfl_xor(q, off);
  }
  __shared__ float rs_[4], rq_[4];
  const int wave = tid >> 6;
  if ((tid & 63) == 0) { rs_[wave] = s; rq_[wave] = q; }
  __syncthreads();
  s = rs_[0] + rs_[1] + rs_[2] + rs_[3];
  q = rq_[0] + rq_[1] + rq_[2] + rq_[3];
  const float mu = s * (1.0f / 768.0f);
  const float var = q * (1.0f / 768.0f) - mu * mu;
  const float rsig = rsqrtf(var + 1e-5f);
  _Float16* out = Acat + (size_t)row * 6912;
#pragma unroll
  for (int i = 0; i < 3; ++i) {
    const int c = tid + i * 256;
    const float x = xv[i];
    const float h = (x - mu) * rsig * lnw[c] + lnb[c];
    union { h8 v; _Float16 u[8]; } bs;
#pragma unroll
    for (int g = 0; g < 8; ++g) {
      const float gv = -2.0f + (4.0f / 7.0f) * (float)g;
      const float t = (h - gv) * 1.75f;  // 1/DENOM = 7/4
      bs.u[g] = (_Float16)__expf(-t * t);
    }
    *(h8*)(out + c * 8) = bs.v;
    out[6144 + c] = (_Float16)(x / (1.0f + __expf(-x)));  // silu
  }
}

// ---------- weight cast + FRAGMENT-SWIZZLE: W fp32 [K][N] -> Bp fp16 in exact
// MFMA B-fragment order: 16B frag (n, k..k+7) at elem addr
//   ((n>>5)*nkt + (k>>6))*2048 + (((k>>4)&3)*64 + (n&31) + 32*((k>>3)&1))*8
__global__ __launch_bounds__(256)
void wt_cast(const float* __restrict__ W, _Float16* __restrict__ Bp,
             int N, int koff, int nkt) {
  __shared__ float t[32][33];
  const int k0 = blockIdx.x * 32, n0 = blockIdx.y * 32;
  const int tx = threadIdx.x & 31, ty = threadIdx.x >> 5;
#pragma unroll
  for (int i = 0; i < 4; ++i)
    t[ty + i * 8][tx] = W[(size_t)(k0 + ty + i * 8) * N + n0 + tx];
  __syncthreads();
  const int f = threadIdx.x;
  if (f < 128) {
    const int nn = f & 31, cc = f >> 5;          // cc: which 8-elem k-chunk
    union { h8 v; _Float16 u[8]; } bs;
#pragma unroll
    for (int j = 0; j < 8; ++j) bs.u[j] = (_Float16)t[cc * 8 + j][nn];
    const int kg = koff + k0 + cc * 8;           // global k of chunk start
    const int nt = (n0 + nn) >> 5;
    const size_t addr = ((size_t)nt * nkt + (kg >> 6)) * 2048 +
                        (size_t)((((kg >> 4) & 3) * 64 + nn + 32 * ((kg >> 3) & 1))) * 8;
    *(h8*)(Bp + addr) = bs.v;
  }
}

// ---------- V transpose: qkv fp16 [8192][2304] -> Vt [96*64][1024]
__global__ __launch_bounds__(256)
void v_transpose(const _Float16* __restrict__ qkv, _Float16* __restrict__ Vt) {
  const int bh = blockIdx.z, hh = bh % 12, b = bh / 12;
  const int kvb = blockIdx.x * 32, db = blockIdx.y * 32;
  __shared__ _Float16 t[32][33];
  const int tx = threadIdx.x & 31, ty = threadIdx.x >> 5;
#pragma unroll
  for (int i = 0; i < 4; ++i) {
    const int kv = kvb + ty + i * 8;
    t[ty + i * 8][tx] = qkv[(size_t)(b * 1024 + kv) * 2304 + 1536 + hh * 64 + db + tx];
  }
  __syncthreads();
#pragma unroll
  for (int i = 0; i < 4; ++i) {
    const int d = db + ty + i * 8;
    Vt[(size_t)(bh * 64 + d) * 1024 + kvb + tx] = t[tx][ty + i * 8];
  }
}

// ---------- fp16 GEMM, r7 EXACT (verified 329 us QKV / ~110 us proj, r5
// anchor 707 total). GEMM LANE CLOSED: r8/r9/r10/r12/r13 (counted vmcnt,
// 3-buf, 256-tiles, A-first order) ALL regressed — at 2 blocks/CU the m114
// inter-block overlap already covers the drain; structure changes only
// perturb the compiler schedule. Do not touch.
#define LOAD_B(dst)                                       \
  {                                                       \
    _Pragma("unroll") for (int ni = 0; ni < 2; ++ni) {    \
      _Pragma("unroll") for (int ks = 0; ks < 4; ++ks)    \
        dst[ni][ks] = *(const h8*)(bpp[ni] + ks * 512);   \
      bpp[ni] += 2048;                                    \
    }                                                     \
  }
#define LOAD_A(buf)                                       \
  {                                                       \
    _Pragma("unroll") for (int i = 0; i < 4; ++i) {       \
      gld16(ap[i], (buf) + alOff[i]);                     \
      ap[i] += 64;                                        \
    }                                                     \
  }
#define MFMA_STEP(buf, br)                                \
  {                                                       \
    const h8* A8 = (const h8*)(buf);                      \
    _Pragma("unroll") for (int ks = 0; ks < 4; ++ks) {    \
      const int o = (ks * 2 + half) ^ swz;                \
      h8 af0 = A8[(wm + l31) * 8 + o];                    \
      h8 af1 = A8[(wm + 32 + l31) * 8 + o];               \
      acc[0][0] = __builtin_amdgcn_mfma_f32_32x32x16_f16(af0, br[0][ks], acc[0][0], 0, 0, 0); \
      acc[0][1] = __builtin_amdgcn_mfma_f32_32x32x16_f16(af0, br[1][ks], acc[0][1], 0, 0, 0); \
      acc[1][0] = __builtin_amdgcn_mfma_f32_32x32x16_f16(af1, br[0][ks], acc[1][0], 0, 0, 0); \
      acc[1][1] = __builtin_amdgcn_mfma_f32_32x32x16_f16(af1, br[1][ks], acc[1][1], 0, 0, 0); \
    }                                                     \
  }

template <bool F16OUT>
__global__ __launch_bounds__(256, 2)
void gemm_bt(const _Float16* __restrict__ A, const _Float16* __restrict__ Bp,
             const float* __restrict__ bias, void* __restrict__ Cout,
             int N, int ldK, int kLen, size_t sliceStride) {
  __shared__ __align__(16) _Float16 As[2 * 128 * 64];
  _Float16* As0 = As;
  _Float16* As1 = As + 128 * 64;
  const int tid = threadIdx.x;
  const int lane = tid & 63, wave = tid >> 6;
  const int gx = gridDim.x;
  const int lin = blockIdx.y * gx + blockIdx.x;
  const int xcd = lin & 7, pos = lin >> 3;
  const int bandH = gridDim.y >> 3;
  const int bm = (xcd * bandH + pos / gx) * 128;
  const int bn = (pos % gx) * 128;
  const int slice = blockIdx.z;
  const int kOff = slice * kLen;
  const int rsub = lane >> 3;
  const int l7 = lane & 7;
  const int l31 = lane & 31, half = lane >> 5;
  const int wm = (wave >> 1) * 64, wn = (wave & 1) * 64;
  const _Float16* ap[4];
  int alOff[4];
#pragma unroll
  for (int i = 0; i < 4; ++i) {
    const int ch = wave * 4 + i;
    const int ksw = (l7 ^ rsub ^ ((ch & 3) << 1)) * 8;
    ap[i] = A + (size_t)(bm + ch * 8 + rsub) * ldK + kOff + ksw;
    alOff[i] = ch * 512;
  }
  const size_t nktTot = (size_t)(ldK >> 6);
  const int kt0 = kOff >> 6;
  const _Float16* bpp[2];
#pragma unroll
  for (int ni = 0; ni < 2; ++ni)
    bpp[ni] = Bp + ((size_t)((bn >> 5) + (wn >> 5) + ni) * nktTot + kt0) * 2048 + lane * 8;

  f16f acc[2][2] = {};
  const int swz = l7 ^ ((rsub & 3) << 1);
  const int nkt = kLen >> 6;
  h8 bregA[2][4], bregB[2][4];
  LOAD_B(bregA);
  LOAD_A(As0);
  for (int kt = 0; kt < nkt; kt += 2) {
    __syncthreads();
    if (kt + 1 < nkt) { LOAD_B(bregB); LOAD_A(As1); }
    MFMA_STEP(As0, bregA);
    __syncthreads();
    if (kt + 2 < nkt) { LOAD_B(bregA); LOAD_A(As0); }
    MFMA_STEP(As1, bregB);
  }
#pragma unroll
  for (int ni = 0; ni < 2; ++ni) {
    const int col = bn + wn + ni * 32 + l31;
    const float bv = bias ? bias[col] : 0.0f;
#pragma unroll
    for (int mi = 0; mi < 2; ++mi) {
      const int rb = bm + wm + mi * 32 + 4 * half;
#pragma unroll
      for (int reg = 0; reg < 16; ++reg) {
        const int r = rb + (reg & 3) + 8 * (reg >> 2);
        const float v = acc[mi][ni][reg] + bv;
        if (F16OUT)
          ((_Float16*)Cout)[(size_t)r * N + col] = (_Float16)v;
        else
          ((float*)Cout + slice * sliceStride)[(size_t)r * N + col] = v;
      }
    }
  }
}

// ---------- flash attention r14: KV-TILE 128 (8 iters instead of 16).
// Q in registers (pattern verified r4); K[128][64] + V[64][128] in LDS
// (50.4KB incl. Ps -> 3 blocks/CU unchanged). Halves barrier count,
// exposed-DMA-drain count, and online-softmax rescale overhead. PV in two
// 64-kv chunks reusing the per-wave P buffer (compiler lgkmcnt orders the
// write->read->write reuse). Scale 0.125 folded into exp args (r4-verified).
// Swizzle: store slot c holds global chunk c^(row&7); read slot kq^(row&7)
// yields global chunk kq — bijective, 2-way bank aliasing only (free, m136).
__global__ __launch_bounds__(256)
void attn(const _Float16* __restrict__ qkv, const _Float16* __restrict__ Vt,
          float* __restrict__ ctx) {
  __shared__ __align__(16) _Float16 Ks[128 * 64];   // [kv][d], 8-row chunks
  __shared__ __align__(16) _Float16 Vs[64 * 128];   // [d][kv], 4-row chunks
  __shared__ __align__(16) _Float16 Ps[4 * 32 * 72];
  const int tid = threadIdx.x;
  const int lane = tid & 63, wave = tid >> 6;
  const int bh = blockIdx.y, hh = bh % 12, b = bh / 12;
  const int qt = blockIdx.x;
  const int rsub = lane >> 3;                 // K staging: row within 8-row chunk
  const int l7 = lane & 7;
  const int ksw = (l7 ^ rsub) * 8;            // K store swizzle (row&7 == rsub)
  const int l16 = lane & 15, quad = lane >> 4, r7 = l16 & 7;
  const int l15 = lane & 15, q4 = lane >> 4;  // V staging: 16 lanes/row, 4 rows/chunk
  // Q fragments direct to regs: lane (l16,quad): rows wave*32+mi*16+l16,
  // k-chunk ks*4+quad (16x16x32 A-frag: row=l&15, k-chunk=l>>4).
  h8 qreg[2][2];
#pragma unroll
  for (int mi = 0; mi < 2; ++mi)
#pragma unroll
    for (int ks = 0; ks < 2; ++ks) {
      const size_t row = (size_t)(b * 1024 + qt * 128 + wave * 32 + mi * 16 + l16);
      qreg[mi][ks] = *(const h8*)(qkv + row * 2304 + hh * 64 + (ks * 4 + quad) * 8);
    }
  f4 acc_o[2][4] = {};
  float m_old[2][4], l_sum[2][4];
#pragma unroll
  for (int mi = 0; mi < 2; ++mi)
#pragma unroll
    for (int j = 0; j < 4; ++j) { m_old[mi][j] = -1e30f; l_sum[mi][j] = 0.0f; }

  _Float16* Pw = Ps + wave * (32 * 72);

  for (int it = 0; it < 8; ++it) {
    const int kv0 = it * 128;
    // stage K: 16 chunks x (8 kv-rows x 64 d), 4 per wave
#pragma unroll
    for (int i = 0; i < 4; ++i) {
      const int ch = wave * 4 + i;
      const int row = ch * 8 + rsub;          // kv 0..127
      gld16(qkv + (size_t)(b * 1024 + kv0 + row) * 2304 + 768 + hh * 64 + ksw,
            Ks + ch * 512);
    }
    // stage V: 16 chunks x (4 d-rows x 128 kv), 4 per wave
#pragma unroll
    for (int i = 0; i < 4; ++i) {
      const int chv = wave * 4 + i;
      const int d = chv * 4 + q4;             // 0..63
      const int csw = l15 ^ (d & 7);          // source col-chunk pre-swizzle
      gld16(Vt + (size_t)(bh * 64 + d) * 1024 + kv0 + csw * 8, Vs + chv * 512);
    }
    __syncthreads();
    const h8* K8 = (const h8*)Ks;
    const h8* V8 = (const h8*)Vs;
    // QK^T: s[mi][ni] over 8 kv-tiles of 16
    f4 s[2][8] = {};
    __builtin_amdgcn_s_setprio(1);
#pragma unroll
    for (int ks = 0; ks < 2; ++ks) {
      const int kq = (ks * 4 + quad) ^ r7;
      h8 kf[8];
#pragma unroll
      for (int ni = 0; ni < 8; ++ni) kf[ni] = K8[(ni * 16 + l16) * 8 + kq];
#pragma unroll
      for (int mi = 0; mi < 2; ++mi)
#pragma unroll
        for (int ni = 0; ni < 8; ++ni)
          s[mi][ni] = __builtin_amdgcn_mfma_f32_16x16x32_f16(qreg[mi][ks], kf[ni], s[mi][ni], 0, 0, 0);
    }
    __builtin_amdgcn_s_setprio(0);
    // online softmax on raw scores; 0.125 folded into exp args (monotone)
#pragma unroll
    for (int mi = 0; mi < 2; ++mi) {
#pragma unroll
      for (int j = 0; j < 4; ++j) {
        float vm = s[mi][0][j];
#pragma unroll
        for (int ni = 1; ni < 8; ++ni) vm = fmaxf(vm, s[mi][ni][j]);
#pragma unroll
        for (int off = 1; off < 16; off <<= 1) vm = fmaxf(vm, __shfl_xor(vm, off));
        const float mn = fmaxf(m_old[mi][j], vm);
        const float alpha = __expf((m_old[mi][j] - mn) * 0.125f);
        float rs = 0.0f;
#pragma unroll
        for (int ni = 0; ni < 8; ++ni) {
          const float p = __expf((s[mi][ni][j] - mn) * 0.125f);
          s[mi][ni][j] = p;
          rs += p;
        }
#pragma unroll
        for (int off = 1; off < 16; off <<= 1) rs += __shfl_xor(rs, off);
        l_sum[mi][j] = l_sum[mi][j] * alpha + rs;
        m_old[mi][j] = mn;
#pragma unroll
        for (int ni = 0; ni < 4; ++ni) acc_o[mi][ni][j] *= alpha;
      }
    }
    // PV in two 64-kv halves, reusing the per-wave P buffer
#pragma unroll
    for (int hf = 0; hf < 2; ++hf) {
#pragma unroll
      for (int mi = 0; mi < 2; ++mi)
#pragma unroll
        for (int ni = 0; ni < 4; ++ni)
#pragma unroll
          for (int j = 0; j < 4; ++j)
            Pw[(mi * 16 + quad * 4 + j) * 72 + ni * 16 + l16] =
                (_Float16)s[mi][hf * 4 + ni][j];
      __builtin_amdgcn_s_setprio(1);
#pragma unroll
      for (int ks = 0; ks < 2; ++ks) {
        const int kq = hf * 8 + ks * 4 + quad;  // kv-chunk within 128
        h8 pf[2], vf[4];
#pragma unroll
        for (int mi = 0; mi < 2; ++mi)
          pf[mi] = *(const h8*)(Pw + (mi * 16 + l16) * 72 + (ks * 4 + quad) * 8);
#pragma unroll
        for (int nd = 0; nd < 4; ++nd)
          vf[nd] = V8[(nd * 16 + l16) * 16 + (kq ^ r7)];
#pragma unroll
        for (int mi = 0; mi < 2; ++mi)
#pragma unroll
          for (int nd = 0; nd < 4; ++nd)
            acc_o[mi][nd] = __builtin_amdgcn_mfma_f32_16x16x32_f16(pf[mi], vf[nd], acc_o[mi][nd], 0, 0, 0);
      }
      __builtin_amdgcn_s_setprio(0);
    }
    __syncthreads();
  }
#pragma unroll
  for (int mi = 0; mi < 2; ++mi) {
#pragma unroll
    for (int j = 0; j < 4; ++j) {
      const float inv = 1.0f / l_sum[mi][j];
      const int tok = b * 1024 + qt * 128 + wave * 32 + mi * 16 + quad * 4 + j;
      float* cr = ctx + (size_t)tok * 768 + hh * 64;
#pragma unroll
      for (int ni = 0; ni < 4; ++ni) cr[ni * 16 + l16] = acc_o[mi][ni][j] * inv;
    }
  }
}

extern "C" void kernel_launch(void* const* d_in, const int* in_sizes, int n_in,
                              void* d_out, int out_size, void* d_ws, size_t ws_size,
                              hipStream_t stream) {
  (void)in_sizes; (void)n_in; (void)out_size; (void)ws_size;
  const float* x    = (const float*)d_in[0];
  const float* qlnw = (const float*)d_in[1];
  const float* qlnb = (const float*)d_in[2];
  const float* qsw  = (const float*)d_in[3];
  const float* qbw  = (const float*)d_in[4];
  const float* qbb  = (const float*)d_in[5];
  const float* plnw = (const float*)d_in[6];
  const float* plnb = (const float*)d_in[7];
  const float* psw  = (const float*)d_in[8];
  const float* pbw  = (const float*)d_in[9];
  const float* pbb  = (const float*)d_in[10];
  float* out = (float*)d_out;

  // workspace layout (fp16 unless noted), ~231 MB total
  _Float16* WtQ  = (_Float16*)d_ws;                  // [2304][6912] fragment-order
  _Float16* WtP  = WtQ + (size_t)2304 * 6912;        // [768][6912] fragment-order
  _Float16* Acat = WtP + (size_t)768 * 6912;         // [8192][6912] (reused)
  _Float16* QKV  = Acat + (size_t)8192 * 6912;       // [8192][2304]
  _Float16* Vt   = QKV + (size_t)8192 * 2304;        // [96*64][1024]
  float* CTX = (float*)(Vt + (size_t)96 * 64 * 1024);  // [8192][768] fp32

  dim3 blk(256);
  // weights -> fp16, fragment-swizzled (K total 6912 -> nkt=108)
  wt_cast<<<dim3(192, 72), blk, 0, stream>>>(qsw, WtQ, 2304, 0, 108);
  wt_cast<<<dim3(24, 72),  blk, 0, stream>>>(qbw, WtQ, 2304, 6144, 108);
  wt_cast<<<dim3(192, 24), blk, 0, stream>>>(psw, WtP, 768, 0, 108);
  wt_cast<<<dim3(24, 24),  blk, 0, stream>>>(pbw, WtP, 768, 6144, 108);
  // FastKAN 1 -> qkv
  kan_prep<<<8192, blk, 0, stream>>>(x, qlnw, qlnb, Acat);
  gemm_bt<true><<<dim3(2304 / 128, 8192 / 128, 1), blk, 0, stream>>>(
      Acat, WtQ, qbb, QKV, 2304, 6912, 6912, 0);
  // attention (r14: KV-tile 128)
  v_transpose<<<dim3(32, 2, 96), blk, 0, stream>>>(QKV, Vt);
  attn<<<dim3(8, 96), blk, 0, stream>>>(QKV, Vt, CTX);
  // FastKAN 2 -> out (single slice K=6912, bias in epilogue)
  kan_prep<<<8192, blk, 0, stream>>>(CTX, plnw, plnb, Acat);
  gemm_bt<false><<<dim3(768 / 128, 8192 / 128, 1), blk, 0, stream>>>(
      Acat, WtP, pbb, out, 768, 6912, 6912, 0);
}

// Round 9
// 718.441 us; speedup vs baseline: 1.0508x; 1.0208x over previous
//
#include <hip/hip_runtime.h>
#include <cstdint>
#include <cstddef>

typedef _Float16 h8 __attribute__((ext_vector_type(8)));
typedef float f4 __attribute__((ext_vector_type(4)));
typedef float f16f __attribute__((ext_vector_type(16)));

#define DEV static __device__ __forceinline__

DEV void gld16(const void* g, void* l) {
  __builtin_amdgcn_global_load_lds(
      (const __attribute__((address_space(1))) void*)g,
      (__attribute__((address_space(3))) void*)l, 16, 0, 0);
}

// ---------- FastKAN prep: LayerNorm + RBF basis + SiLU -> Acat [M][6912] fp16
__global__ __launch_bounds__(256)
void kan_prep(const float* __restrict__ X, const float* __restrict__ lnw,
              const float* __restrict__ lnb, _Float16* __restrict__ Acat) {
  const int row = blockIdx.x;
  const int tid = threadIdx.x;
  const float* xr = X + (size_t)row * 768;
  float xv[3];
  xv[0] = xr[tid]; xv[1] = xr[tid + 256]; xv[2] = xr[tid + 512];
  float s = xv[0] + xv[1] + xv[2];
  float q = xv[0] * xv[0] + xv[1] * xv[1] + xv[2] * xv[2];
#pragma unroll
  for (int off = 32; off; off >>= 1) {
    s += __shfl_xor(s, off);
    q += __shfl_xor(q, off);
  }
  __shared__ float rs_[4], rq_[4];
  const int wave = tid >> 6;
  if ((tid & 63) == 0) { rs_[wave] = s; rq_[wave] = q; }
  __syncthreads();
  s = rs_[0] + rs_[1] + rs_[2] + rs_[3];
  q = rq_[0] + rq_[1] + rq_[2] + rq_[3];
  const float mu = s * (1.0f / 768.0f);
  const float var = q * (1.0f / 768.0f) - mu * mu;
  const float rsig = rsqrtf(var + 1e-5f);
  _Float16* out = Acat + (size_t)row * 6912;
#pragma unroll
  for (int i = 0; i < 3; ++i) {
    const int c = tid + i * 256;
    const float x = xv[i];
    const float h = (x - mu) * rsig * lnw[c] + lnb[c];
    union { h8 v; _Float16 u[8]; } bs;
#pragma unroll
    for (int g = 0; g < 8; ++g) {
      const float gv = -2.0f + (4.0f / 7.0f) * (float)g;
      const float t = (h - gv) * 1.75f;  // 1/DENOM = 7/4
      bs.u[g] = (_Float16)__expf(-t * t);
    }
    *(h8*)(out + c * 8) = bs.v;
    out[6144 + c] = (_Float16)(x / (1.0f + __expf(-x)));  // silu
  }
}

// ---------- weight cast + FRAGMENT-SWIZZLE: W fp32 [K][N] -> Bp fp16 in exact
// MFMA B-fragment order: 16B frag (n, k..k+7) at elem addr
//   ((n>>5)*nkt + (k>>6))*2048 + (((k>>4)&3)*64 + (n&31) + 32*((k>>3)&1))*8
__global__ __launch_bounds__(256)
void wt_cast(const float* __restrict__ W, _Float16* __restrict__ Bp,
             int N, int koff, int nkt) {
  __shared__ float t[32][33];
  const int k0 = blockIdx.x * 32, n0 = blockIdx.y * 32;
  const int tx = threadIdx.x & 31, ty = threadIdx.x >> 5;
#pragma unroll
  for (int i = 0; i < 4; ++i)
    t[ty + i * 8][tx] = W[(size_t)(k0 + ty + i * 8) * N + n0 + tx];
  __syncthreads();
  const int f = threadIdx.x;
  if (f < 128) {
    const int nn = f & 31, cc = f >> 5;          // cc: which 8-elem k-chunk
    union { h8 v; _Float16 u[8]; } bs;
#pragma unroll
    for (int j = 0; j < 8; ++j) bs.u[j] = (_Float16)t[cc * 8 + j][nn];
    const int kg = koff + k0 + cc * 8;           // global k of chunk start
    const int nt = (n0 + nn) >> 5;
    const size_t addr = ((size_t)nt * nkt + (kg >> 6)) * 2048 +
                        (size_t)((((kg >> 4) & 3) * 64 + nn + 32 * ((kg >> 3) & 1))) * 8;
    *(h8*)(Bp + addr) = bs.v;
  }
}

// ---------- V transpose: qkv fp16 [8192][2304] -> Vt [96*64][1024]
__global__ __launch_bounds__(256)
void v_transpose(const _Float16* __restrict__ qkv, _Float16* __restrict__ Vt) {
  const int bh = blockIdx.z, hh = bh % 12, b = bh / 12;
  const int kvb = blockIdx.x * 32, db = blockIdx.y * 32;
  __shared__ _Float16 t[32][33];
  const int tx = threadIdx.x & 31, ty = threadIdx.x >> 5;
#pragma unroll
  for (int i = 0; i < 4; ++i) {
    const int kv = kvb + ty + i * 8;
    t[ty + i * 8][tx] = qkv[(size_t)(b * 1024 + kv) * 2304 + 1536 + hh * 64 + db + tx];
  }
  __syncthreads();
#pragma unroll
  for (int i = 0; i < 4; ++i) {
    const int d = db + ty + i * 8;
    Vt[(size_t)(bh * 64 + d) * 1024 + kvb + tx] = t[tx][ty + i * 8];
  }
}

// ---------- fp16 GEMM, r7 EXACT (verified 329-330 us QKV / ~127 us proj).
// GEMM LANE CLOSED: r8/r9/r10/r12/r13 all regressed — at 2 blocks/CU the
// m114 inter-block overlap already covers the drain. Do not touch.
#define LOAD_B(dst)                                       \
  {                                                       \
    _Pragma("unroll") for (int ni = 0; ni < 2; ++ni) {    \
      _Pragma("unroll") for (int ks = 0; ks < 4; ++ks)    \
        dst[ni][ks] = *(const h8*)(bpp[ni] + ks * 512);   \
      bpp[ni] += 2048;                                    \
    }                                                     \
  }
#define LOAD_A(buf)                                       \
  {                                                       \
    _Pragma("unroll") for (int i = 0; i < 4; ++i) {       \
      gld16(ap[i], (buf) + alOff[i]);                     \
      ap[i] += 64;                                        \
    }                                                     \
  }
#define MFMA_STEP(buf, br)                                \
  {                                                       \
    const h8* A8 = (const h8*)(buf);                      \
    _Pragma("unroll") for (int ks = 0; ks < 4; ++ks) {    \
      const int o = (ks * 2 + half) ^ swz;                \
      h8 af0 = A8[(wm + l31) * 8 + o];                    \
      h8 af1 = A8[(wm + 32 + l31) * 8 + o];               \
      acc[0][0] = __builtin_amdgcn_mfma_f32_32x32x16_f16(af0, br[0][ks], acc[0][0], 0, 0, 0); \
      acc[0][1] = __builtin_amdgcn_mfma_f32_32x32x16_f16(af0, br[1][ks], acc[0][1], 0, 0, 0); \
      acc[1][0] = __builtin_amdgcn_mfma_f32_32x32x16_f16(af1, br[0][ks], acc[1][0], 0, 0, 0); \
      acc[1][1] = __builtin_amdgcn_mfma_f32_32x32x16_f16(af1, br[1][ks], acc[1][1], 0, 0, 0); \
    }                                                     \
  }

template <bool F16OUT>
__global__ __launch_bounds__(256, 2)
void gemm_bt(const _Float16* __restrict__ A, const _Float16* __restrict__ Bp,
             const float* __restrict__ bias, void* __restrict__ Cout,
             int N, int ldK, int kLen, size_t sliceStride) {
  __shared__ __align__(16) _Float16 As[2 * 128 * 64];
  _Float16* As0 = As;
  _Float16* As1 = As + 128 * 64;
  const int tid = threadIdx.x;
  const int lane = tid & 63, wave = tid >> 6;
  const int gx = gridDim.x;
  const int lin = blockIdx.y * gx + blockIdx.x;
  const int xcd = lin & 7, pos = lin >> 3;
  const int bandH = gridDim.y >> 3;
  const int bm = (xcd * bandH + pos / gx) * 128;
  const int bn = (pos % gx) * 128;
  const int slice = blockIdx.z;
  const int kOff = slice * kLen;
  const int rsub = lane >> 3;
  const int l7 = lane & 7;
  const int l31 = lane & 31, half = lane >> 5;
  const int wm = (wave >> 1) * 64, wn = (wave & 1) * 64;
  const _Float16* ap[4];
  int alOff[4];
#pragma unroll
  for (int i = 0; i < 4; ++i) {
    const int ch = wave * 4 + i;
    const int ksw = (l7 ^ rsub ^ ((ch & 3) << 1)) * 8;
    ap[i] = A + (size_t)(bm + ch * 8 + rsub) * ldK + kOff + ksw;
    alOff[i] = ch * 512;
  }
  const size_t nktTot = (size_t)(ldK >> 6);
  const int kt0 = kOff >> 6;
  const _Float16* bpp[2];
#pragma unroll
  for (int ni = 0; ni < 2; ++ni)
    bpp[ni] = Bp + ((size_t)((bn >> 5) + (wn >> 5) + ni) * nktTot + kt0) * 2048 + lane * 8;

  f16f acc[2][2] = {};
  const int swz = l7 ^ ((rsub & 3) << 1);
  const int nkt = kLen >> 6;
  h8 bregA[2][4], bregB[2][4];
  LOAD_B(bregA);
  LOAD_A(As0);
  for (int kt = 0; kt < nkt; kt += 2) {
    __syncthreads();
    if (kt + 1 < nkt) { LOAD_B(bregB); LOAD_A(As1); }
    MFMA_STEP(As0, bregA);
    __syncthreads();
    if (kt + 2 < nkt) { LOAD_B(bregA); LOAD_A(As0); }
    MFMA_STEP(As1, bregB);
  }
#pragma unroll
  for (int ni = 0; ni < 2; ++ni) {
    const int col = bn + wn + ni * 32 + l31;
    const float bv = bias ? bias[col] : 0.0f;
#pragma unroll
    for (int mi = 0; mi < 2; ++mi) {
      const int rb = bm + wm + mi * 32 + 4 * half;
#pragma unroll
      for (int reg = 0; reg < 16; ++reg) {
        const int r = rb + (reg & 3) + 8 * (reg >> 2);
        const float v = acc[mi][ni][reg] + bv;
        if (F16OUT)
          ((_Float16*)Cout)[(size_t)r * N + col] = (_Float16)v;
        else
          ((float*)Cout + slice * sliceStride)[(size_t)r * N + col] = v;
      }
    }
  }
}

// ---------- flash attention r15: r7 structure with TWO surgical changes.
// (1) K double-buffered (2x8KB) — the per-iter DMA is issued a FULL
//     iteration ahead, so the top-of-iter vmcnt(0) drain is pre-covered
//     (r7 drained a just-issued DMA, ~800 cyc exposed x16 iters).
// (2) V NOT staged — PV reads V fragments directly from global Vt (clean
//     unswizzled h8 loads; V panel is L2-resident, reused by 8 q-tile
//     blocks; same direct-from-global pattern as the GEMM's B loads;
//     Common-mistake #7: don't stage L2-fit data).
// Q stays in LDS exactly as r7 (both Q-to-regs attempts regressed).
// LDS = Q 16K + Kdbuf 16K + Ps 18K = 50.25KB -> 3 blocks/CU unchanged.
// ONE barrier per iter: lgkmcnt(0) retires all ds_reads of the buffer
// about to be overwritten; barrier orders the overwrite across waves.
// Softmax numerics r7-exact.
__global__ __launch_bounds__(256)
void attn(const _Float16* __restrict__ qkv, const _Float16* __restrict__ Vt,
          float* __restrict__ ctx) {
  __shared__ __align__(16) _Float16 Qs[128 * 64];
  __shared__ __align__(16) _Float16 Ks[2][64 * 64];
  __shared__ __align__(16) _Float16 Ps[4 * 32 * 72];
  const int tid = threadIdx.x;
  const int lane = tid & 63, wave = tid >> 6;
  const int bh = blockIdx.y, hh = bh % 12, b = bh / 12;
  const int qt = blockIdx.x;
  const int rsub = lane >> 3;
  const int ksw = ((lane & 7) ^ rsub) * 8;
#pragma unroll
  for (int i = 0; i < 4; ++i) {
    const int ch = wave * 4 + i;
    const int row = ch * 8 + rsub;
    gld16(qkv + (size_t)(b * 1024 + qt * 128 + row) * 2304 + hh * 64 + ksw, Qs + ch * 512);
  }
  // K(0) -> Ks[0]
#pragma unroll
  for (int i = 0; i < 2; ++i) {
    const int ch = wave * 2 + i;
    const int row = ch * 8 + rsub;
    gld16(qkv + (size_t)(b * 1024 + row) * 2304 + 768 + hh * 64 + ksw, Ks[0] + ch * 512);
  }
  const int l16 = lane & 15, quad = lane >> 4, r7 = l16 & 7;
  f4 acc_o[2][4] = {};
  float m_old[2][4], l_sum[2][4];
#pragma unroll
  for (int mi = 0; mi < 2; ++mi)
#pragma unroll
    for (int j = 0; j < 4; ++j) { m_old[mi][j] = -1e30f; l_sum[mi][j] = 0.0f; }

  _Float16* Pw = Ps + wave * (32 * 72);
  const _Float16* vbase = Vt + (size_t)bh * 64 * 1024;

  for (int it = 0; it < 16; ++it) {
    const int kv0 = it * 64;
    // drain K(it) DMA (issued one full iter earlier; it=0: prologue) and
    // retire all ds_reads of the buffer about to be overwritten.
    asm volatile("s_waitcnt vmcnt(0) lgkmcnt(0)" ::: "memory");
    __builtin_amdgcn_s_barrier();
    if (it < 15) {
      const int kvn = kv0 + 64;
#pragma unroll
      for (int i = 0; i < 2; ++i) {
        const int ch = wave * 2 + i;
        const int row = ch * 8 + rsub;
        gld16(qkv + (size_t)(b * 1024 + kvn + row) * 2304 + 768 + hh * 64 + ksw,
              Ks[(it + 1) & 1] + ch * 512);
      }
    }
    const h8* Q8 = (const h8*)Qs;
    const h8* K8 = (const h8*)Ks[it & 1];
    f4 s[2][4] = {};
    __builtin_amdgcn_s_setprio(1);
#pragma unroll
    for (int ks = 0; ks < 2; ++ks) {
      const int kq = (ks * 4 + quad) ^ r7;
      h8 qf[2], kf[4];
#pragma unroll
      for (int mi = 0; mi < 2; ++mi) qf[mi] = Q8[(wave * 32 + mi * 16 + l16) * 8 + kq];
#pragma unroll
      for (int ni = 0; ni < 4; ++ni) kf[ni] = K8[(ni * 16 + l16) * 8 + kq];
#pragma unroll
      for (int mi = 0; mi < 2; ++mi)
#pragma unroll
        for (int ni = 0; ni < 4; ++ni)
          s[mi][ni] = __builtin_amdgcn_mfma_f32_16x16x32_f16(qf[mi], kf[ni], s[mi][ni], 0, 0, 0);
    }
    __builtin_amdgcn_s_setprio(0);
#pragma unroll
    for (int mi = 0; mi < 2; ++mi)
#pragma unroll
      for (int ni = 0; ni < 4; ++ni) s[mi][ni] *= 0.125f;  // d^-0.5, d=64
#pragma unroll
    for (int mi = 0; mi < 2; ++mi) {
#pragma unroll
      for (int j = 0; j < 4; ++j) {
        float vm = fmaxf(fmaxf(s[mi][0][j], s[mi][1][j]), fmaxf(s[mi][2][j], s[mi][3][j]));
#pragma unroll
        for (int off = 1; off < 16; off <<= 1) vm = fmaxf(vm, __shfl_xor(vm, off));
        const float mn = fmaxf(m_old[mi][j], vm);
        const float alpha = __expf(m_old[mi][j] - mn);
        float rs = 0.0f;
#pragma unroll
        for (int ni = 0; ni < 4; ++ni) {
          const float p = __expf(s[mi][ni][j] - mn);
          s[mi][ni][j] = p;
          rs += p;
        }
#pragma unroll
        for (int off = 1; off < 16; off <<= 1) rs += __shfl_xor(rs, off);
        l_sum[mi][j] = l_sum[mi][j] * alpha + rs;
        m_old[mi][j] = mn;
#pragma unroll
        for (int ni = 0; ni < 4; ++ni) acc_o[mi][ni][j] *= alpha;
      }
    }
#pragma unroll
    for (int mi = 0; mi < 2; ++mi)
#pragma unroll
      for (int ni = 0; ni < 4; ++ni)
#pragma unroll
        for (int j = 0; j < 4; ++j)
          Pw[(mi * 16 + quad * 4 + j) * 72 + ni * 16 + l16] = (_Float16)s[mi][ni][j];
    __builtin_amdgcn_s_setprio(1);
#pragma unroll
    for (int ks = 0; ks < 2; ++ks) {
      const int kq = ks * 4 + quad;
      h8 pf[2], vf[4];
#pragma unroll
      for (int mi = 0; mi < 2; ++mi) pf[mi] = *(const h8*)(Pw + (mi * 16 + l16) * 72 + kq * 8);
#pragma unroll
      for (int ni = 0; ni < 4; ++ni)
        vf[ni] = *(const h8*)(vbase + (size_t)(ni * 16 + l16) * 1024 + kv0 + kq * 8);
#pragma unroll
      for (int mi = 0; mi < 2; ++mi)
#pragma unroll
        for (int ni = 0; ni < 4; ++ni)
          acc_o[mi][ni] = __builtin_amdgcn_mfma_f32_16x16x32_f16(pf[mi], vf[ni], acc_o[mi][ni], 0, 0, 0);
    }
    __builtin_amdgcn_s_setprio(0);
  }
#pragma unroll
  for (int mi = 0; mi < 2; ++mi) {
#pragma unroll
    for (int j = 0; j < 4; ++j) {
      const float inv = 1.0f / l_sum[mi][j];
      const int tok = b * 1024 + qt * 128 + wave * 32 + mi * 16 + quad * 4 + j;
      float* cr = ctx + (size_t)tok * 768 + hh * 64;
#pragma unroll
      for (int ni = 0; ni < 4; ++ni) cr[ni * 16 + l16] = acc_o[mi][ni][j] * inv;
    }
  }
}

extern "C" void kernel_launch(void* const* d_in, const int* in_sizes, int n_in,
                              void* d_out, int out_size, void* d_ws, size_t ws_size,
                              hipStream_t stream) {
  (void)in_sizes; (void)n_in; (void)out_size; (void)ws_size;
  const float* x    = (const float*)d_in[0];
  const float* qlnw = (const float*)d_in[1];
  const float* qlnb = (const float*)d_in[2];
  const float* qsw  = (const float*)d_in[3];
  const float* qbw  = (const float*)d_in[4];
  const float* qbb  = (const float*)d_in[5];
  const float* plnw = (const float*)d_in[6];
  const float* plnb = (const float*)d_in[7];
  const float* psw  = (const float*)d_in[8];
  const float* pbw  = (const float*)d_in[9];
  const float* pbb  = (const float*)d_in[10];
  float* out = (float*)d_out;

  // workspace layout (fp16 unless noted), ~231 MB total
  _Float16* WtQ  = (_Float16*)d_ws;                  // [2304][6912] fragment-order
  _Float16* WtP  = WtQ + (size_t)2304 * 6912;        // [768][6912] fragment-order
  _Float16* Acat = WtP + (size_t)768 * 6912;         // [8192][6912] (reused)
  _Float16* QKV  = Acat + (size_t)8192 * 6912;       // [8192][2304]
  _Float16* Vt   = QKV + (size_t)8192 * 2304;        // [96*64][1024]
  float* CTX = (float*)(Vt + (size_t)96 * 64 * 1024);  // [8192][768] fp32

  dim3 blk(256);
  // weights -> fp16, fragment-swizzled (K total 6912 -> nkt=108)
  wt_cast<<<dim3(192, 72), blk, 0, stream>>>(qsw, WtQ, 2304, 0, 108);
  wt_cast<<<dim3(24, 72),  blk, 0, stream>>>(qbw, WtQ, 2304, 6144, 108);
  wt_cast<<<dim3(192, 24), blk, 0, stream>>>(psw, WtP, 768, 0, 108);
  wt_cast<<<dim3(24, 24),  blk, 0, stream>>>(pbw, WtP, 768, 6144, 108);
  // FastKAN 1 -> qkv
  kan_prep<<<8192, blk, 0, stream>>>(x, qlnw, qlnb, Acat);
  gemm_bt<true><<<dim3(2304 / 128, 8192 / 128, 1), blk, 0, stream>>>(
      Acat, WtQ, qbb, QKV, 2304, 6912, 6912, 0);
  // attention (r15: K dbuf + V direct-from-global)
  v_transpose<<<dim3(32, 2, 96), blk, 0, stream>>>(QKV, Vt);
  attn<<<dim3(8, 96), blk, 0, stream>>>(QKV, Vt, CTX);
  // FastKAN 2 -> out (single slice K=6912, bias in epilogue)
  kan_prep<<<8192, blk, 0, stream>>>(CTX, plnw, plnb, Acat);
  gemm_bt<false><<<dim3(768 / 128, 8192 / 128, 1), blk, 0, stream>>>(
      Acat, WtP, pbb, out, 768, 6912, 6912, 0);
}